// Round 9
// baseline (1156.849 us; speedup 1.0000x reference)
//
#include <hip/hip_runtime.h>
#include <hip/hip_bf16.h>
#include <math.h>

// ---------------------------------------------------------------------------
// DNC forward on MI355X.
//   k_detect  : device-side input-dtype detection (f32 vs bf16) + bar zero
//   k_convert : canonicalize all inputs -> internal bf16/f32 buffers
//   k_main    : FUSED producer/consumer kernel, 128 blocks x 512 threads:
//               blocks 0-63  = persistent LSTM (waves 0-3) + xi GEMM tiles
//                              (waves 4-7, for t-2), 34 producer grid barriers
//               blocks 64-127= memory recurrence (1 block/batch), gated on a
//                              read-mostly progress line (XI[t] @ prog>=t+3)
//               barrier cnt / gen / progress on separate 128B cachelines
//   k_tanhy   : tanh([out, rvec]) -> bf16
//   k_out     : output GEMM (2048 x 256 x 768) MFMA -> d_out (dtype per flag)
// ---------------------------------------------------------------------------

typedef __bf16 bf16_t;
typedef __attribute__((ext_vector_type(8))) __bf16 bf16x8;
typedef __attribute__((ext_vector_type(4))) float f32x4;

#define B_    64
#define T_    32
#define IN_   256
#define H_    512
#define M_    256
#define W_    64
#define R_    4
#define IFACE_ 471
#define DELTA_ 1e-6f

// ---------------- ws layout (bytes) ----------------
#define OFF_H0SEQ  (0L)
#define SZ_H0SEQ   (32L*64*512*2)
#define OFF_OUTSEQ (OFF_H0SEQ + SZ_H0SEQ)
#define SZ_OUTSEQ  (32L*64*512*2)
#define OFF_H0BUF  (OFF_OUTSEQ + SZ_OUTSEQ)
#define SZ_HBUF    (2L*64*512*2)
#define OFF_H1BUF  (OFF_H0BUF + SZ_HBUF)
#define OFF_XI     (OFF_H1BUF + SZ_HBUF)
#define SZ_XI      (32L*64*480*4)
#define OFF_RVEC   (OFF_XI + SZ_XI)
#define SZ_RVEC    (32L*64*256*4)
#define OFF_YBF    (OFF_RVEC + SZ_RVEC)
#define SZ_YBF     (32L*64*768*2)
#define OFF_BAR    (OFF_YBF + SZ_YBF)
#define SZ_BAR     (512L)   // [0]=cnt line, [32]=gen line, [64]=progress line; flag @ +8
#define OFF_XB     (OFF_BAR + SZ_BAR)
#define SZ_XB      (64L*32*256*2)
#define OFF_H0B    (OFF_XB + SZ_XB)
#define SZ_H0B     (2L*64*512*2)
#define OFF_W0     (OFF_H0B + SZ_H0B)
#define SZ_W       (2048L*512*2)
#define OFF_W1     (OFF_W0 + SZ_W)
#define OFF_W2     (OFF_W1 + SZ_W)
#define OFF_W3     (OFF_W2 + SZ_W)
#define OFF_WIF    (OFF_W3 + SZ_W)
#define SZ_WIF     (480L*512*2)
#define OFF_WOUTB  (OFF_WIF + SZ_WIF)
#define SZ_WOUTB   (256L*768*2)
#define OFF_BS0    (OFF_WOUTB + SZ_WOUTB)
#define SZ_BS      (2048L*4)
#define OFF_BS1    (OFF_BS0 + SZ_BS)
#define OFF_BIF    (OFF_BS1 + SZ_BS)
#define SZ_BIF     (2048L)
#define OFF_BOUTF  (OFF_BIF + SZ_BIF)
#define SZ_BOUTF   (1024L)

__device__ __forceinline__ float sigf(float x){ return 1.0f/(1.0f + expf(-x)); }
__device__ __forceinline__ float softplusf(float x){
  return fmaxf(x, 0.0f) + log1pf(expf(-fabsf(x)));
}
__device__ __forceinline__ float wred(float v){
  #pragma unroll
  for (int off = 32; off; off >>= 1) v += __shfl_xor(v, off, 64);
  return v;
}
__device__ __forceinline__ float ldin(const void* p, long i, int mf){
  return mf ? ((const float*)p)[i] : (float)((const bf16_t*)p)[i];
}

// agent-scope generation barrier; cnt and gen on SEPARATE cachelines so the
// arrival RMWs don't invalidate the pollers' shared copy of gen.
__device__ __forceinline__ void gridbar(unsigned* cnt, unsigned* gen, unsigned nb){
  __syncthreads();
  if (threadIdx.x == 0){
    unsigned g = __hip_atomic_load(gen, __ATOMIC_ACQUIRE, __HIP_MEMORY_SCOPE_AGENT);
    unsigned a = __hip_atomic_fetch_add(cnt, 1u, __ATOMIC_ACQ_REL, __HIP_MEMORY_SCOPE_AGENT);
    if (a == nb - 1u){
      __hip_atomic_store(cnt, 0u, __ATOMIC_RELAXED, __HIP_MEMORY_SCOPE_AGENT);
      __hip_atomic_fetch_add(gen, 1u, __ATOMIC_ACQ_REL, __HIP_MEMORY_SCOPE_AGENT);
    } else {
      while (__hip_atomic_load(gen, __ATOMIC_ACQUIRE, __HIP_MEMORY_SCOPE_AGENT) == g)
        __builtin_amdgcn_s_sleep(2);
    }
  }
  __syncthreads();
}

// ---------------------------------------------------------------------------
__global__ void k_detect(const unsigned short* __restrict__ x16,
                         int* __restrict__ flag, unsigned* __restrict__ bar){
  __shared__ int cnt;
  if (threadIdx.x == 0){ cnt = 0; bar[0] = 0u; bar[32] = 0u; bar[64] = 0u; }
  __syncthreads();
  unsigned short u = x16[threadIdx.x * 2];
  int e = (u >> 7) & 0xFF;
  if (e >= 0x88) atomicAdd(&cnt, 1);
  __syncthreads();
  if (threadIdx.x == 0) *flag = (cnt > 16) ? 1 : 0;
}

// ---------------------------------------------------------------------------
__global__ void k_convert(const void* x, const void* h0, const void* Wih0,
                          const void* Whh0, const void* bih0, const void* bhh0,
                          const void* Wih1, const void* Whh1, const void* bih1,
                          const void* bhh1, const void* Wif, const void* bif,
                          const void* Wout, const void* bout,
                          bf16_t* __restrict__ xb, bf16_t* __restrict__ h0b,
                          bf16_t* __restrict__ h0buf, bf16_t* __restrict__ h1buf,
                          bf16_t* __restrict__ W0, bf16_t* __restrict__ W1,
                          bf16_t* __restrict__ W2, bf16_t* __restrict__ W3,
                          bf16_t* __restrict__ Wifp, bf16_t* __restrict__ Woutb,
                          float* __restrict__ bs0, float* __restrict__ bs1,
                          float* __restrict__ bifp, float* __restrict__ boutf,
                          const int* __restrict__ flag)
{
  const int mf = *flag;
  const long stride = (long)gridDim.x * blockDim.x;
  long i0 = (long)blockIdx.x * blockDim.x + threadIdx.x;
  switch (blockIdx.y){
  case 0: for (long i = i0; i < 64L*32*256; i += stride) xb[i] = (bf16_t)ldin(x, i, mf); break;
  case 1: for (long i = i0; i < 2L*64*512; i += stride){
            float v = ldin(h0, i, mf); bf16_t bb = (bf16_t)v; h0b[i] = bb;
            if (i < 64*512) h0buf[i] = bb; else h1buf[i - 64*512] = bb;
          } break;
  case 2: for (long i = i0; i < 2048L*512; i += stride) W0[i] = (bf16_t)ldin(Wih0, i, mf); break;
  case 3: for (long i = i0; i < 2048L*512; i += stride) W1[i] = (bf16_t)ldin(Whh0, i, mf); break;
  case 4: for (long i = i0; i < 2048L*512; i += stride) W2[i] = (bf16_t)ldin(Wih1, i, mf); break;
  case 5: for (long i = i0; i < 2048L*512; i += stride) W3[i] = (bf16_t)ldin(Whh1, i, mf); break;
  case 6: for (long i = i0; i < 480L*512; i += stride){
            long r = i >> 9;
            Wifp[i] = (r < IFACE_) ? (bf16_t)ldin(Wif, i, mf) : (bf16_t)0.0f;
          } break;
  case 7: for (long i = i0; i < 256L*768; i += stride) Woutb[i] = (bf16_t)ldin(Wout, i, mf); break;
  case 8:
    for (long i = i0; i < 2048; i += stride){
      bs0[i] = ldin(bih0, i, mf) + ldin(bhh0, i, mf);
      bs1[i] = ldin(bih1, i, mf) + ldin(bhh1, i, mf);
    }
    for (long i = i0; i < 480; i += stride) bifp[i] = (i < IFACE_) ? ldin(bif, i, mf) : 0.0f;
    for (long i = i0; i < 256; i += stride) boutf[i] = ldin(bout, i, mf);
    break;
  }
}

// ---------------------------------------------------------------------------
__device__ __forceinline__ void softmax256_wave(float* a, int lane){
  float v0=a[lane], v1=a[64+lane], v2=a[128+lane], v3=a[192+lane];
  float mx = fmaxf(fmaxf(v0,v1), fmaxf(v2,v3));
  #pragma unroll
  for (int off=32; off; off>>=1) mx = fmaxf(mx, __shfl_xor(mx, off, 64));
  v0=expf(v0-mx); v1=expf(v1-mx); v2=expf(v2-mx); v3=expf(v3-mx);
  float s = v0+v1+v2+v3;
  #pragma unroll
  for (int off=32; off; off>>=1) s += __shfl_xor(s, off, 64);
  float inv = 1.0f/s;
  a[lane]=v0*inv; a[64+lane]=v1*inv; a[128+lane]=v2*inv; a[192+lane]=v3*inv;
}

// ---- LDS overlays -------------------------------------------------------
struct ProdShm {
  bf16_t wpool[66560];     // 133 KB weight pool
  float  cst[64][16];
  float  bias[4][16];
};
struct ConsShm {
  float smem[256][65];
  float xib[480];
  float rkn4r[2][65][4];
  float wkn[64], ev_[64], wvv[64];
  float rs_[4], fg_[4], rm_[4][3];
  float wsS, agS, wgS, wwsumS;
  float invn[256], wcw[256];
  float usage[256], uu[256], su[256], scanA[256];
  int   rank_[256];
  float ww_[256], prec_[256];
  float rw_[4][256];
  float rw4[256][4];
  float fwd_[4][256], bwd_[4][256], rcw_[4][256];
  bf16_t rwb[4][264];
  bf16_t wwb[256], precb[256];
  float p2cT[2][264];
  float p5cT[5][2][264];
  float rvp[8][4][64];
};
union ShUnion { ProdShm p; ConsShm c; };

// ---------------------------------------------------------------------------
// Fused producer/consumer kernel.  128 blocks x 512 threads.
__global__ __launch_bounds__(512,2) void k_main(
    const bf16_t* __restrict__ xb, const bf16_t* __restrict__ h0b,
    const bf16_t* __restrict__ W0, const bf16_t* __restrict__ W1,
    const bf16_t* __restrict__ W2, const bf16_t* __restrict__ W3,
    const float* __restrict__ bs0, const float* __restrict__ bs1,
    const bf16_t* __restrict__ Wifp, const float* __restrict__ bifp,
    bf16_t* __restrict__ h0buf, bf16_t* __restrict__ h1buf,
    bf16_t* __restrict__ h0seq, bf16_t* __restrict__ outseq,
    float* __restrict__ XI, float* __restrict__ RVEC,
    unsigned* __restrict__ bar)
{
  __shared__ ShUnion sh;
  const int bid = blockIdx.x;
  const int tid = threadIdx.x, lane = tid & 63, wv = tid >> 6;
  const int m16 = lane & 15, q = lane >> 4;

  if (bid < 64){
    // ===================== PRODUCER: LSTM + xi tiles ======================
    ProdShm& P = sh.p;
    const int layer = bid >> 5;
    const int u0 = (bid & 31) * 16;

    if (!layer){
      for (int i = tid; i < 64*32; i += 512){
        int rl = i >> 5, c8 = (i & 31)*8;
        int grow = (rl >> 4)*512 + u0 + (rl & 15);
        *(bf16x8*)&P.wpool[rl*264 + c8] = *(const bf16x8*)(W0 + (size_t)grow*512 + c8);
      }
      for (int i = tid; i < 64*64; i += 512){
        int rl = i >> 6, c8 = (i & 63)*8;
        int grow = (rl >> 4)*512 + u0 + (rl & 15);
        *(bf16x8*)&P.wpool[16896 + rl*520 + c8] = *(const bf16x8*)(W1 + (size_t)grow*512 + c8);
      }
    } else {
      for (int i = tid; i < 64*64; i += 512){
        int rl = i >> 6, c8 = (i & 63)*8;
        int grow = (rl >> 4)*512 + u0 + (rl & 15);
        *(bf16x8*)&P.wpool[rl*520 + c8]         = *(const bf16x8*)(W2 + (size_t)grow*512 + c8);
        *(bf16x8*)&P.wpool[33280 + rl*520 + c8] = *(const bf16x8*)(W3 + (size_t)grow*512 + c8);
      }
    }
    for (int i = tid; i < 64*16; i += 512){
      int b = i >> 4, n = i & 15;
      P.cst[b][n] = (float)h0b[layer*(64*512) + b*512 + u0 + n];
    }
    if (tid < 64){
      int G = tid >> 4, n = tid & 15;
      const float* bs = layer ? bs1 : bs0;
      P.bias[G][n] = bs[G*512 + u0 + n];
    }
    __syncthreads();

    bf16_t* hbuf = layer ? h1buf : h0buf;

    for (int ps = 0; ps <= 33; ++ps){
      if (wv < 4){
        const int t = layer ? (ps - 1) : ps;
        const bool active = layer ? (ps >= 1 && ps <= 32) : (ps < 32);
        if (active){
          const int p = t & 1;
          const bf16_t* hin = hbuf + p*(64*512);
          bf16_t* hout = hbuf + (p^1)*(64*512);
          const int b0 = wv * 16;

          f32x4 acc[4];
          #pragma unroll
          for (int G = 0; G < 4; ++G){ float bv = P.bias[G][m16]; acc[G] = (f32x4){bv,bv,bv,bv}; }

          if (!layer){
            #pragma unroll 2
            for (int kt = 0; kt < 8; ++kt){
              bf16x8 a = *(const bf16x8*)(xb + ((size_t)(b0+m16)*T_ + t)*IN_ + kt*32 + q*8);
              #pragma unroll
              for (int G = 0; G < 4; ++G)
                acc[G] = __builtin_amdgcn_mfma_f32_16x16x32_bf16(
                    a, *(const bf16x8*)&P.wpool[(G*16+m16)*264 + kt*32 + q*8], acc[G], 0, 0, 0);
            }
            #pragma unroll 4
            for (int kt = 0; kt < 16; ++kt){
              bf16x8 a = *(const bf16x8*)(hin + (b0+m16)*512 + kt*32 + q*8);
              #pragma unroll
              for (int G = 0; G < 4; ++G)
                acc[G] = __builtin_amdgcn_mfma_f32_16x16x32_bf16(
                    a, *(const bf16x8*)&P.wpool[16896 + (G*16+m16)*520 + kt*32 + q*8], acc[G], 0, 0, 0);
            }
          } else {
            #pragma unroll 4
            for (int kt = 0; kt < 16; ++kt){
              bf16x8 a = *(const bf16x8*)(h0seq + ((size_t)t*64 + b0+m16)*512 + kt*32 + q*8);
              #pragma unroll
              for (int G = 0; G < 4; ++G)
                acc[G] = __builtin_amdgcn_mfma_f32_16x16x32_bf16(
                    a, *(const bf16x8*)&P.wpool[(G*16+m16)*520 + kt*32 + q*8], acc[G], 0, 0, 0);
            }
            #pragma unroll 4
            for (int kt = 0; kt < 16; ++kt){
              bf16x8 a = *(const bf16x8*)(hin + (b0+m16)*512 + kt*32 + q*8);
              #pragma unroll
              for (int G = 0; G < 4; ++G)
                acc[G] = __builtin_amdgcn_mfma_f32_16x16x32_bf16(
                    a, *(const bf16x8*)&P.wpool[33280 + (G*16+m16)*520 + kt*32 + q*8], acc[G], 0, 0, 0);
            }
          }
          #pragma unroll
          for (int v = 0; v < 4; ++v){
            int b = b0 + q*4 + v;
            float gi = acc[0][v], gf = acc[1][v], gg = acc[2][v], go = acc[3][v];
            float c_ = sigf(gf)*P.cst[b][m16] + sigf(gi)*tanhf(gg);
            P.cst[b][m16] = c_;
            float h = sigf(go)*tanhf(c_);
            bf16_t hb = (bf16_t)h;
            hout[b*512 + u0 + m16] = hb;
            if (!layer) h0seq[((size_t)t*64 + b)*512 + u0 + m16] = hb;
            else        outseq[((size_t)t*64 + b)*512 + u0 + m16] = hb;
          }
        }
      } else if (ps >= 2 && bid < 30){
        // xi tile for t2 = ps-2: rows bid*16..+16, batch-tile per wave
        const int t2 = ps - 2;
        const int b0 = (wv - 4) * 16;
        const int r = bid*16 + m16;          // < 480 (rows 471..479 zero-padded)
        float bv = bifp[r];
        f32x4 acc = {bv,bv,bv,bv};
        const bf16_t* arow = outseq + ((size_t)t2*64 + b0 + m16)*512 + q*8;
        const bf16_t* brow = Wifp + (size_t)r*512 + q*8;
        #pragma unroll 4
        for (int kt = 0; kt < 16; ++kt){
          acc = __builtin_amdgcn_mfma_f32_16x16x32_bf16(
              *(const bf16x8*)(arow + kt*32), *(const bf16x8*)(brow + kt*32), acc, 0, 0, 0);
        }
        #pragma unroll
        for (int v = 0; v < 4; ++v)
          XI[((size_t)t2*64 + b0 + q*4 + v)*480 + r] = acc[v];
      }
      gridbar(bar, bar + 32, 64);
      // publish progress on its own read-mostly line (block 0 only)
      if (bid == 0 && tid == 0)
        __hip_atomic_store(bar + 64, (unsigned)(ps + 1), __ATOMIC_RELEASE,
                           __HIP_MEMORY_SCOPE_AGENT);
    }
  } else {
    // ===================== CONSUMER: memory recurrence ====================
    ConsShm& S = sh.c;
    const int b = bid - 64;
    const int quad = lane >> 4, li = lane & 15;
    unsigned prog = 0;   // tid0's cached view of the progress counter

    bf16x8 rowL[2][8], colL[2][8];
    #pragma unroll
    for (int g = 0; g < 2; ++g)
      #pragma unroll
      for (int ch = 0; ch < 8; ++ch)
        #pragma unroll
        for (int z = 0; z < 8; ++z){ rowL[g][ch][z] = (bf16_t)0.0f; colL[g][ch][z] = (bf16_t)0.0f; }

    if (tid < 256){
      S.ww_[tid] = DELTA_; S.usage[tid] = 0.0f; S.prec_[tid] = 0.0f;
      S.invn[tid] = 1.0f/(sqrtf(64.0f*DELTA_*DELTA_) + DELTA_);
      S.wwb[tid] = (bf16_t)DELTA_; S.precb[tid] = (bf16_t)0.0f;
      #pragma unroll
      for (int r = 0; r < 4; ++r) S.rw_[r][tid] = DELTA_;
    }
    for (int i = tid; i < 4*264; i += 512) ((bf16_t*)S.rwb)[i] = (bf16_t)DELTA_;
    for (int i = tid; i < 256*65; i += 512) ((float*)S.smem)[i] = DELTA_;
    __syncthreads();

    const int mH = tid >> 1, q2 = tid & 1;

    for (int t = 0; t < 32; ++t){
      // ---- R1: wait for XI[t] (progress >= t+3), then load ----
      if (tid == 0 && prog < (unsigned)(t + 3)){
        for (;;){
          prog = __hip_atomic_load(bar + 64, __ATOMIC_ACQUIRE, __HIP_MEMORY_SCOPE_AGENT);
          if (prog >= (unsigned)(t + 3)) break;
          __builtin_amdgcn_s_sleep(8);
        }
      }
      __syncthreads();
      if (tid < IFACE_) S.xib[tid] = XI[((size_t)t*64 + b)*480 + tid];
      __syncthreads();

      // ---- R2: parse interface vector ----
      if (wv < 4){
        float v = tanhf(S.xib[wv*64 + lane]);
        float s = wred(v*v);
        float vn = v/(sqrtf(s) + DELTA_);
        S.rkn4r[0][lane][wv] = vn; S.rkn4r[1][lane][wv] = vn;
      } else if (wv == 4){
        float v = tanhf(S.xib[260 + lane]);
        float s = wred(v*v);
        S.wkn[lane] = v/(sqrtf(s) + DELTA_);
      } else if (wv == 5){ S.ev_[lane] = sigf(S.xib[325 + lane]);
      } else if (wv == 6){ S.wvv[lane] = tanhf(S.xib[389 + lane]);
      } else {
        if (lane < 4)        S.rs_[lane] = softplusf(S.xib[256 + lane]);
        else if (lane == 4)  S.wsS = softplusf(S.xib[324]);
        else if (lane < 9)   S.fg_[lane-5] = sigf(S.xib[453 + (lane-5)]);
        else if (lane == 9)  S.agS = sigf(S.xib[457]);
        else if (lane == 10) S.wgS = sigf(S.xib[458]);
        else if (lane >= 16 && lane < 20){
          int r = lane - 16;
          float a0 = S.xib[459+r*3], a1 = S.xib[459+r*3+1], a2 = S.xib[459+r*3+2];
          float mx = fmaxf(a0, fmaxf(a1, a2));
          float e0 = expf(a0-mx), e1 = expf(a1-mx), e2 = expf(a2-mx);
          float s = e0+e1+e2;
          S.rm_[r][0]=e0/s; S.rm_[r][1]=e1/s; S.rm_[r][2]=e2/s;
        }
      }
      __syncthreads();

      // ---- R3: usage update (tid<256) + write-content partials (all) ----
      if (tid < 256){
        int m = tid;
        float us = S.usage[m] + (1.0f - S.usage[m])*S.ww_[m];
        float psi = (1.0f - S.fg_[0]*S.rw_[0][m]) * (1.0f - S.fg_[1]*S.rw_[1][m])
                  * (1.0f - S.fg_[2]*S.rw_[2][m]) * (1.0f - S.fg_[3]*S.rw_[3][m]);
        us *= psi;
        S.usage[m] = us;
        S.uu[m] = DELTA_ + (1.0f - DELTA_)*us;
      }
      { float acc = 0.0f;
        #pragma unroll
        for (int it = 0; it < 32; ++it){
          int w = q2*32 + it;
          acc += S.smem[mH][w] * S.wkn[w];
        }
        S.p2cT[q2][mH] = acc; }
      __syncthreads();

      // ---- R4: wave0: wcw combine + softmax ; waves 4-7: rank-sort ----
      if (wv == 0){
        #pragma unroll
        for (int z = 0; z < 4; ++z){
          int m = z*64 + lane;
          S.wcw[m] = S.wsS * (S.p2cT[0][m] + S.p2cT[1][m]) * S.invn[m];
        }
        softmax256_wave(S.wcw, lane);
      } else if (tid >= 256){
        const int i = tid - 256;
        const float ui = S.uu[i];
        int cnt = 0;
        #pragma unroll 8
        for (int k = 0; k < 64; ++k){
          f32x4 u4 = *(const f32x4*)&S.uu[k*4];
          #pragma unroll
          for (int z = 0; z < 4; ++z){
            int j = k*4 + z; float uj = u4[z];
            cnt += (uj < ui || (uj == ui && j < i)) ? 1 : 0;
          }
        }
        S.rank_[i] = cnt;
        S.su[cnt] = ui;
      }
      __syncthreads();

      // ---- R5: exclusive product scan of su -> scanA (wave 0) ----
      if (wv == 0){
        int base = lane*4;
        float v0 = S.su[base], v1 = S.su[base+1], v2 = S.su[base+2];
        float p1 = v0*v1, p2 = p1*v2, p3 = p2*S.su[base+3];
        float sc = p3;
        #pragma unroll
        for (int off = 1; off < 64; off <<= 1){
          float n = __shfl_up(sc, off, 64);
          if (lane >= off) sc *= n;
        }
        float exch = __shfl_up(sc, 1, 64);
        if (lane == 0) exch = 1.0f;
        S.scanA[base] = exch; S.scanA[base+1] = exch*v0;
        S.scanA[base+2] = exch*p1; S.scanA[base+3] = exch*p2;
      }
      __syncthreads();

      // ---- R7: ww (redundant per half) + mem erase/write + partials ----
      { const int m = mH;
        float al = (1.0f - S.uu[m]) * S.scanA[S.rank_[m]];
        float wm = S.wgS*(S.agS*al + (1.0f - S.agS)*S.wcw[m]);
        if (q2 == 0){ S.ww_[m] = wm; S.wwb[m] = (bf16_t)wm; }
        float s2 = 0.0f, sr0 = 0.0f, sr1 = 0.0f, sr2 = 0.0f, sr3 = 0.0f;
        #pragma unroll
        for (int it = 0; it < 32; ++it){
          int w = q2*32 + it;
          float mn = S.smem[m][w]*(1.0f - wm*S.ev_[w]) + wm*S.wvv[w];
          S.smem[m][w] = mn;
          s2 += mn*mn;
          f32x4 rk = *(const f32x4*)&S.rkn4r[q2][w][0];
          sr0 += mn*rk[0]; sr1 += mn*rk[1]; sr2 += mn*rk[2]; sr3 += mn*rk[3];
        }
        S.p5cT[0][q2][m] = s2;
        S.p5cT[1][q2][m] = sr0; S.p5cT[2][q2][m] = sr1;
        S.p5cT[3][q2][m] = sr2; S.p5cT[4][q2][m] = sr3; }
      __syncthreads();

      // ---- R8: norm + read-content pre-softmax (tid<256); wave4: wwsum ----
      if (tid < 256){
        int m = tid;
        float s2 = S.p5cT[0][0][m] + S.p5cT[0][1][m];
        float inv = 1.0f/(sqrtf(s2) + DELTA_);
        S.invn[m] = inv;
        #pragma unroll
        for (int r = 0; r < 4; ++r){
          float sr = S.p5cT[r+1][0][m] + S.p5cT[r+1][1][m];
          S.rcw_[r][m] = S.rs_[r]*sr*inv;
        }
      } else if (wv == 4){
        float s = wred(S.ww_[lane] + S.ww_[64+lane] + S.ww_[128+lane] + S.ww_[192+lane]);
        if (lane == 0) S.wwsumS = s;
      }
      __syncthreads();

      // ---- R9: link update + fwd/bwd via MFMA ----
      { float wown[2], pown[2], alpha[2];
        #pragma unroll
        for (int g = 0; g < 2; ++g){
          int o = wv*32 + g*16 + li;
          wown[g] = (float)S.wwb[o]; pown[g] = (float)S.precb[o];
          alpha[g] = 1.0f - wown[g];
        }
        f32x4 facc[2] = {{0,0,0,0},{0,0,0,0}}, bacc[2] = {{0,0,0,0},{0,0,0,0}};
        #pragma unroll
        for (int ch = 0; ch < 8; ++ch){
          const int cbase = ch*32 + quad*8;
          bf16x8 rwf = *(const bf16x8*)&S.rwb[li & 3][cbase];
          bf16x8 wwv = *(const bf16x8*)&S.wwb[cbase];
          bf16x8 pcv = *(const bf16x8*)&S.precb[cbase];
          float wcf[8], pcf[8];
          #pragma unroll
          for (int jj = 0; jj < 8; ++jj){ wcf[jj] = (float)wwv[jj]; pcf[jj] = (float)pcv[jj]; }
          #pragma unroll
          for (int g = 0; g < 2; ++g){
            const int o = wv*32 + g*16 + li;
            bf16x8 rl = rowL[g][ch];
            bf16x8 cl = colL[g][ch];
            #pragma unroll
            for (int jj = 0; jj < 8; ++jj){
              const int c = cbase + jj;
              float s = alpha[g] - wcf[jj];
              float vr = s*(float)rl[jj] + wown[g]*pcf[jj];
              float vc = s*(float)cl[jj] + wcf[jj]*pown[g];
              if (c == o){ vr = 0.0f; vc = 0.0f; }
              rl[jj] = (bf16_t)vr;
              cl[jj] = (bf16_t)vc;
            }
            rowL[g][ch] = rl; colL[g][ch] = cl;
            facc[g] = __builtin_amdgcn_mfma_f32_16x16x32_bf16(rl, rwf, facc[g], 0, 0, 0);
            bacc[g] = __builtin_amdgcn_mfma_f32_16x16x32_bf16(rwf, cl, bacc[g], 0, 0, 0);
          }
        }
        #pragma unroll
        for (int g = 0; g < 2; ++g){
          if (li < 4){
            #pragma unroll
            for (int z = 0; z < 4; ++z) S.fwd_[li][wv*32 + g*16 + quad*4 + z] = facc[g][z];
          }
          if (quad == 0){
            #pragma unroll
            for (int z = 0; z < 4; ++z) S.bwd_[z][wv*32 + g*16 + li] = bacc[g][z];
          }
        }
      }
      __syncthreads();

      // ---- R10: waves0-3: rcw softmax ; waves4-7: precedence ----
      if (wv < 4) softmax256_wave(S.rcw_[wv], lane);
      else {
        int m = tid - 256;
        float p = (1.0f - S.wwsumS)*S.prec_[m] + S.ww_[m];
        S.prec_[m] = p;
        S.precb[m] = (bf16_t)p;
      }
      __syncthreads();

      // ---- R11: new read weights ----
      { int r = tid >> 7, m0 = (tid & 127)*2;
        #pragma unroll
        for (int z = 0; z < 2; ++z){
          int m = m0 + z;
          float v = S.rm_[r][0]*S.bwd_[r][m] + S.rm_[r][1]*S.fwd_[r][m] + S.rm_[r][2]*S.rcw_[r][m];
          S.rw_[r][m] = v;
          S.rw4[m][r] = v;
          S.rwb[r][m] = (bf16_t)v;
        } }
      __syncthreads();

      // ---- R12: read vectors: wave-per-32-rows ----
      { float r0 = 0, r1 = 0, r2 = 0, r3 = 0;
        #pragma unroll
        for (int k = 0; k < 32; ++k){
          int m = wv*32 + k;
          f32x4 r4 = *(const f32x4*)&S.rw4[m][0];
          float mv = S.smem[m][lane];
          r0 += r4[0]*mv; r1 += r4[1]*mv; r2 += r4[2]*mv; r3 += r4[3]*mv;
        }
        S.rvp[wv][0][lane] = r0; S.rvp[wv][1][lane] = r1;
        S.rvp[wv][2][lane] = r2; S.rvp[wv][3][lane] = r3; }
      __syncthreads();

      // ---- R13: combine + store ----
      if (tid < 256){
        const int w = tid & 63, r = tid >> 6;
        float v = 0.0f;
        #pragma unroll
        for (int c = 0; c < 8; ++c) v += S.rvp[c][r][w];
        RVEC[((size_t)t*64 + b)*256 + tid] = v;
      }
      __syncthreads();
    }
  }
}

// ---------------------------------------------------------------------------
__global__ void k_tanhy(const bf16_t* __restrict__ outseq, const float* __restrict__ RVEC,
                        bf16_t* __restrict__ Y){
  const int n = 2048*768;
  for (int i = blockIdx.x*blockDim.x + threadIdx.x; i < n; i += gridDim.x*blockDim.x){
    int row = i / 768, j = i - row*768;
    float v = (j < 512) ? (float)outseq[(size_t)row*512 + j] : RVEC[(size_t)row*256 + (j - 512)];
    Y[i] = (bf16_t)tanhf(v);
  }
}

__global__ __launch_bounds__(256,1) void k_out(
    const bf16_t* __restrict__ Y, const bf16_t* __restrict__ Woutb,
    const float* __restrict__ boutf, void* __restrict__ dout,
    const int* __restrict__ flag)
{
  const int mf = *flag;
  const int mt = blockIdx.x;          // 0..127
  const int tid = threadIdx.x, lane = tid & 63, wv = tid >> 6;
  const int nt = blockIdx.y*4 + wv;   // 0..15
  const int m16 = lane & 15, q = lane >> 4;
  const int o = nt*16 + m16;
  float bv = boutf[o];
  f32x4 acc = {bv,bv,bv,bv};
  const bf16_t* arow = Y + (size_t)(mt*16 + m16)*768 + q*8;
  const bf16_t* brow = Woutb + (size_t)o*768 + q*8;
  for (int kt = 0; kt < 24; ++kt){
    acc = __builtin_amdgcn_mfma_f32_16x16x32_bf16(
        *(const bf16x8*)(arow + kt*32), *(const bf16x8*)(brow + kt*32), acc, 0, 0, 0);
  }
  #pragma unroll
  for (int v = 0; v < 4; ++v){
    int row = mt*16 + q*4 + v;        // = t*64 + b
    int b = row & 63, t = row >> 6;
    size_t idx = ((size_t)b*T_ + t)*256 + o;
    if (mf) ((float*)dout)[idx] = acc[v];
    else    ((bf16_t*)dout)[idx] = (bf16_t)acc[v];
  }
}

// ---------------------------------------------------------------------------
extern "C" void kernel_launch(void* const* d_in, const int* in_sizes, int n_in,
                              void* d_out, int out_size, void* d_ws, size_t ws_size,
                              hipStream_t stream)
{
  char* ws = (char*)d_ws;
  bf16_t* H0SEQ  = (bf16_t*)(ws + OFF_H0SEQ);
  bf16_t* OUTSEQ = (bf16_t*)(ws + OFF_OUTSEQ);
  bf16_t* H0BUF  = (bf16_t*)(ws + OFF_H0BUF);
  bf16_t* H1BUF  = (bf16_t*)(ws + OFF_H1BUF);
  float*  XI     = (float*) (ws + OFF_XI);
  float*  RVEC   = (float*) (ws + OFF_RVEC);
  bf16_t* YBF    = (bf16_t*)(ws + OFF_YBF);
  unsigned* BAR  = (unsigned*)(ws + OFF_BAR);
  int*    FLAG   = (int*)   (ws + OFF_BAR + 8);
  bf16_t* XB     = (bf16_t*)(ws + OFF_XB);
  bf16_t* H0B    = (bf16_t*)(ws + OFF_H0B);
  bf16_t* W0     = (bf16_t*)(ws + OFF_W0);
  bf16_t* W1     = (bf16_t*)(ws + OFF_W1);
  bf16_t* W2     = (bf16_t*)(ws + OFF_W2);
  bf16_t* W3     = (bf16_t*)(ws + OFF_W3);
  bf16_t* WIFP   = (bf16_t*)(ws + OFF_WIF);
  bf16_t* WOUTB  = (bf16_t*)(ws + OFF_WOUTB);
  float*  BS0    = (float*) (ws + OFF_BS0);
  float*  BS1    = (float*) (ws + OFF_BS1);
  float*  BIFP   = (float*) (ws + OFF_BIF);
  float*  BOUTF  = (float*) (ws + OFF_BOUTF);

  k_detect<<<1, 256, 0, stream>>>((const unsigned short*)d_in[0], FLAG, BAR);
  k_convert<<<dim3(256, 9), 256, 0, stream>>>(
      d_in[0], d_in[1], d_in[2], d_in[3], d_in[4], d_in[5], d_in[6],
      d_in[7], d_in[8], d_in[9], d_in[10], d_in[11], d_in[12], d_in[13],
      XB, H0B, H0BUF, H1BUF, W0, W1, W2, W3, WIFP, WOUTB,
      BS0, BS1, BIFP, BOUTF, FLAG);
  k_main<<<128, 512, 0, stream>>>(XB, H0B, W0, W1, W2, W3, BS0, BS1,
                                  WIFP, BIFP, H0BUF, H1BUF, H0SEQ, OUTSEQ,
                                  XI, RVEC, BAR);
  k_tanhy<<<512, 256, 0, stream>>>(OUTSEQ, RVEC, YBF);
  k_out<<<dim3(128, 4), 256, 0, stream>>>(YBF, WOUTB, BOUTF, d_out, FLAG);
}

// Round 10
// 1145.420 us; speedup vs baseline: 1.0100x; 1.0100x over previous
//
#include <hip/hip_runtime.h>
#include <hip/hip_bf16.h>
#include <math.h>

// ---------------------------------------------------------------------------
// DNC forward on MI355X.
//   k_detect  : device-side input-dtype detection (f32 vs bf16) + bar zero
//   k_convert : canonicalize all inputs -> internal bf16/f32 buffers
//   k_main    : FUSED producer/consumer kernel, 128 blocks x 512 threads:
//               blocks 0-63  = persistent LSTM (waves 0-3) + xi GEMM tiles
//                              (waves 4-7, for t-2); 34 producer barriers via
//                              a HIERARCHICAL 8x8 tree (monotonic counters)
//               blocks 64-127= memory recurrence (1 block/batch), gated on the
//                              prog line published by the tree-barrier root
//   k_tanhy   : tanh([out, rvec]) -> bf16
//   k_out     : output GEMM (2048 x 256 x 768) MFMA -> d_out (dtype per flag)
// ---------------------------------------------------------------------------

typedef __bf16 bf16_t;
typedef __attribute__((ext_vector_type(8))) __bf16 bf16x8;
typedef __attribute__((ext_vector_type(4))) float f32x4;

#define B_    64
#define T_    32
#define IN_   256
#define H_    512
#define M_    256
#define W_    64
#define R_    4
#define IFACE_ 471
#define DELTA_ 1e-6f

// ---------------- ws layout (bytes) ----------------
#define OFF_H0SEQ  (0L)
#define SZ_H0SEQ   (32L*64*512*2)
#define OFF_OUTSEQ (OFF_H0SEQ + SZ_H0SEQ)
#define SZ_OUTSEQ  (32L*64*512*2)
#define OFF_H0BUF  (OFF_OUTSEQ + SZ_OUTSEQ)
#define SZ_HBUF    (2L*64*512*2)
#define OFF_H1BUF  (OFF_H0BUF + SZ_HBUF)
#define OFF_XI     (OFF_H1BUF + SZ_HBUF)
#define SZ_XI      (32L*64*480*4)
#define OFF_RVEC   (OFF_XI + SZ_XI)
#define SZ_RVEC    (32L*64*256*4)
#define OFF_YBF    (OFF_RVEC + SZ_RVEC)
#define SZ_YBF     (32L*64*768*2)
#define OFF_BAR    (OFF_YBF + SZ_YBF)
// bar layout (unsigned words): cnt_g[i] @ i*32 (i=0..7), cnt_top @ 256,
// gen @ 288, prog @ 320, flag @ word 352.  One 128B line each.
#define SZ_BAR     (2048L)
#define OFF_XB     (OFF_BAR + SZ_BAR)
#define SZ_XB      (64L*32*256*2)
#define OFF_H0B    (OFF_XB + SZ_XB)
#define SZ_H0B     (2L*64*512*2)
#define OFF_W0     (OFF_H0B + SZ_H0B)
#define SZ_W       (2048L*512*2)
#define OFF_W1     (OFF_W0 + SZ_W)
#define OFF_W2     (OFF_W1 + SZ_W)
#define OFF_W3     (OFF_W2 + SZ_W)
#define OFF_WIF    (OFF_W3 + SZ_W)
#define SZ_WIF     (480L*512*2)
#define OFF_WOUTB  (OFF_WIF + SZ_WIF)
#define SZ_WOUTB   (256L*768*2)
#define OFF_BS0    (OFF_WOUTB + SZ_WOUTB)
#define SZ_BS      (2048L*4)
#define OFF_BS1    (OFF_BS0 + SZ_BS)
#define OFF_BIF    (OFF_BS1 + SZ_BS)
#define SZ_BIF     (2048L)
#define OFF_BOUTF  (OFF_BIF + SZ_BIF)
#define SZ_BOUTF   (1024L)

__device__ __forceinline__ float sigf(float x){ return 1.0f/(1.0f + expf(-x)); }
__device__ __forceinline__ float softplusf(float x){
  return fmaxf(x, 0.0f) + log1pf(expf(-fabsf(x)));
}
__device__ __forceinline__ float wred(float v){
  #pragma unroll
  for (int off = 32; off; off >>= 1) v += __shfl_xor(v, off, 64);
  return v;
}
__device__ __forceinline__ float ldin(const void* p, long i, int mf){
  return mf ? ((const float*)p)[i] : (float)((const bf16_t*)p)[i];
}

// Hierarchical 8x8 tree barrier over 64 producer blocks, monotonic counters.
// Group = bid&7 (same-XCD under round-robin placement).  The root publishes
// prog = ps+1 (consumer gate) and bumps gen (producer gate).
__device__ __forceinline__ void treebar64(unsigned* bar, unsigned ps, int bid){
  __syncthreads();
  if (threadIdx.x == 0){
    const unsigned tgt = 8u*(ps + 1u);
    unsigned* cg = bar + ((bid & 7) << 5);
    unsigned a = __hip_atomic_fetch_add(cg, 1u, __ATOMIC_ACQ_REL, __HIP_MEMORY_SCOPE_AGENT);
    if (a == tgt - 1u){
      unsigned b = __hip_atomic_fetch_add(bar + 256, 1u, __ATOMIC_ACQ_REL, __HIP_MEMORY_SCOPE_AGENT);
      if (b == tgt - 1u){
        __hip_atomic_store(bar + 320, ps + 1u, __ATOMIC_RELEASE, __HIP_MEMORY_SCOPE_AGENT);
        __hip_atomic_fetch_add(bar + 288, 1u, __ATOMIC_ACQ_REL, __HIP_MEMORY_SCOPE_AGENT);
      }
    }
    while (__hip_atomic_load(bar + 288, __ATOMIC_ACQUIRE, __HIP_MEMORY_SCOPE_AGENT) < ps + 1u)
      __builtin_amdgcn_s_sleep(1);
  }
  __syncthreads();
}

// ---------------------------------------------------------------------------
__global__ void k_detect(const unsigned short* __restrict__ x16,
                         int* __restrict__ flag, unsigned* __restrict__ bar){
  __shared__ int cnt;
  if (threadIdx.x < 8)       bar[threadIdx.x << 5] = 0u;
  else if (threadIdx.x == 8) bar[256] = 0u;
  else if (threadIdx.x == 9) bar[288] = 0u;
  else if (threadIdx.x == 10) bar[320] = 0u;
  if (threadIdx.x == 0) cnt = 0;
  __syncthreads();
  unsigned short u = x16[threadIdx.x * 2];
  int e = (u >> 7) & 0xFF;
  if (e >= 0x88) atomicAdd(&cnt, 1);
  __syncthreads();
  if (threadIdx.x == 0) *flag = (cnt > 16) ? 1 : 0;
}

// ---------------------------------------------------------------------------
__global__ void k_convert(const void* x, const void* h0, const void* Wih0,
                          const void* Whh0, const void* bih0, const void* bhh0,
                          const void* Wih1, const void* Whh1, const void* bih1,
                          const void* bhh1, const void* Wif, const void* bif,
                          const void* Wout, const void* bout,
                          bf16_t* __restrict__ xb, bf16_t* __restrict__ h0b,
                          bf16_t* __restrict__ h0buf, bf16_t* __restrict__ h1buf,
                          bf16_t* __restrict__ W0, bf16_t* __restrict__ W1,
                          bf16_t* __restrict__ W2, bf16_t* __restrict__ W3,
                          bf16_t* __restrict__ Wifp, bf16_t* __restrict__ Woutb,
                          float* __restrict__ bs0, float* __restrict__ bs1,
                          float* __restrict__ bifp, float* __restrict__ boutf,
                          const int* __restrict__ flag)
{
  const int mf = *flag;
  const long stride = (long)gridDim.x * blockDim.x;
  long i0 = (long)blockIdx.x * blockDim.x + threadIdx.x;
  switch (blockIdx.y){
  case 0: for (long i = i0; i < 64L*32*256; i += stride) xb[i] = (bf16_t)ldin(x, i, mf); break;
  case 1: for (long i = i0; i < 2L*64*512; i += stride){
            float v = ldin(h0, i, mf); bf16_t bb = (bf16_t)v; h0b[i] = bb;
            if (i < 64*512) h0buf[i] = bb; else h1buf[i - 64*512] = bb;
          } break;
  case 2: for (long i = i0; i < 2048L*512; i += stride) W0[i] = (bf16_t)ldin(Wih0, i, mf); break;
  case 3: for (long i = i0; i < 2048L*512; i += stride) W1[i] = (bf16_t)ldin(Whh0, i, mf); break;
  case 4: for (long i = i0; i < 2048L*512; i += stride) W2[i] = (bf16_t)ldin(Wih1, i, mf); break;
  case 5: for (long i = i0; i < 2048L*512; i += stride) W3[i] = (bf16_t)ldin(Whh1, i, mf); break;
  case 6: for (long i = i0; i < 480L*512; i += stride){
            long r = i >> 9;
            Wifp[i] = (r < IFACE_) ? (bf16_t)ldin(Wif, i, mf) : (bf16_t)0.0f;
          } break;
  case 7: for (long i = i0; i < 256L*768; i += stride) Woutb[i] = (bf16_t)ldin(Wout, i, mf); break;
  case 8:
    for (long i = i0; i < 2048; i += stride){
      bs0[i] = ldin(bih0, i, mf) + ldin(bhh0, i, mf);
      bs1[i] = ldin(bih1, i, mf) + ldin(bhh1, i, mf);
    }
    for (long i = i0; i < 480; i += stride) bifp[i] = (i < IFACE_) ? ldin(bif, i, mf) : 0.0f;
    for (long i = i0; i < 256; i += stride) boutf[i] = ldin(bout, i, mf);
    break;
  }
}

// ---------------------------------------------------------------------------
__device__ __forceinline__ void softmax256_wave(float* a, int lane){
  float v0=a[lane], v1=a[64+lane], v2=a[128+lane], v3=a[192+lane];
  float mx = fmaxf(fmaxf(v0,v1), fmaxf(v2,v3));
  #pragma unroll
  for (int off=32; off; off>>=1) mx = fmaxf(mx, __shfl_xor(mx, off, 64));
  v0=expf(v0-mx); v1=expf(v1-mx); v2=expf(v2-mx); v3=expf(v3-mx);
  float s = v0+v1+v2+v3;
  #pragma unroll
  for (int off=32; off; off>>=1) s += __shfl_xor(s, off, 64);
  float inv = 1.0f/s;
  a[lane]=v0*inv; a[64+lane]=v1*inv; a[128+lane]=v2*inv; a[192+lane]=v3*inv;
}

// ---- LDS overlays -------------------------------------------------------
struct ProdShm {
  bf16_t wpool[66560];     // 133 KB weight pool
  float  cst[64][16];
  float  bias[4][16];
};
struct ConsShm {
  float smem[256][65];
  float xib[480];
  float rkn4r[2][65][4];
  float wkn[64], ev_[64], wvv[64];
  float rs_[4], fg_[4], rm_[4][3];
  float wsS, agS, wgS, wwsumS;
  float invn[256], wcw[256];
  float usage[256], uu[256], su[256], scanA[256];
  int   rank_[256];
  float ww_[256], prec_[256];
  float rw_[4][256];
  float rw4[256][4];
  float fwd_[4][256], bwd_[4][256], rcw_[4][256];
  bf16_t rwb[4][264];
  bf16_t wwb[256], precb[256];
  float p2cT[2][264];
  float p5cT[5][2][264];
  float rvp[8][4][64];
};
union ShUnion { ProdShm p; ConsShm c; };

// ---------------------------------------------------------------------------
// Fused producer/consumer kernel.  128 blocks x 512 threads.
__global__ __launch_bounds__(512,2) void k_main(
    const bf16_t* __restrict__ xb, const bf16_t* __restrict__ h0b,
    const bf16_t* __restrict__ W0, const bf16_t* __restrict__ W1,
    const bf16_t* __restrict__ W2, const bf16_t* __restrict__ W3,
    const float* __restrict__ bs0, const float* __restrict__ bs1,
    const bf16_t* __restrict__ Wifp, const float* __restrict__ bifp,
    bf16_t* __restrict__ h0buf, bf16_t* __restrict__ h1buf,
    bf16_t* __restrict__ h0seq, bf16_t* __restrict__ outseq,
    float* __restrict__ XI, float* __restrict__ RVEC,
    unsigned* __restrict__ bar)
{
  __shared__ ShUnion sh;
  const int bid = blockIdx.x;
  const int tid = threadIdx.x, lane = tid & 63, wv = tid >> 6;
  const int m16 = lane & 15, q = lane >> 4;

  if (bid < 64){
    // ===================== PRODUCER: LSTM + xi tiles ======================
    ProdShm& P = sh.p;
    const int layer = bid >> 5;
    const int u0 = (bid & 31) * 16;

    if (!layer){
      for (int i = tid; i < 64*32; i += 512){
        int rl = i >> 5, c8 = (i & 31)*8;
        int grow = (rl >> 4)*512 + u0 + (rl & 15);
        *(bf16x8*)&P.wpool[rl*264 + c8] = *(const bf16x8*)(W0 + (size_t)grow*512 + c8);
      }
      for (int i = tid; i < 64*64; i += 512){
        int rl = i >> 6, c8 = (i & 63)*8;
        int grow = (rl >> 4)*512 + u0 + (rl & 15);
        *(bf16x8*)&P.wpool[16896 + rl*520 + c8] = *(const bf16x8*)(W1 + (size_t)grow*512 + c8);
      }
    } else {
      for (int i = tid; i < 64*64; i += 512){
        int rl = i >> 6, c8 = (i & 63)*8;
        int grow = (rl >> 4)*512 + u0 + (rl & 15);
        *(bf16x8*)&P.wpool[rl*520 + c8]         = *(const bf16x8*)(W2 + (size_t)grow*512 + c8);
        *(bf16x8*)&P.wpool[33280 + rl*520 + c8] = *(const bf16x8*)(W3 + (size_t)grow*512 + c8);
      }
    }
    for (int i = tid; i < 64*16; i += 512){
      int b = i >> 4, n = i & 15;
      P.cst[b][n] = (float)h0b[layer*(64*512) + b*512 + u0 + n];
    }
    if (tid < 64){
      int G = tid >> 4, n = tid & 15;
      const float* bs = layer ? bs1 : bs0;
      P.bias[G][n] = bs[G*512 + u0 + n];
    }
    __syncthreads();

    bf16_t* hbuf = layer ? h1buf : h0buf;

    for (int ps = 0; ps <= 33; ++ps){
      if (wv < 4){
        const int t = layer ? (ps - 1) : ps;
        const bool active = layer ? (ps >= 1 && ps <= 32) : (ps < 32);
        if (active){
          const int p = t & 1;
          const bf16_t* hin = hbuf + p*(64*512);
          bf16_t* hout = hbuf + (p^1)*(64*512);
          const int b0 = wv * 16;

          f32x4 acc[4];
          #pragma unroll
          for (int G = 0; G < 4; ++G){ float bv = P.bias[G][m16]; acc[G] = (f32x4){bv,bv,bv,bv}; }

          if (!layer){
            #pragma unroll 2
            for (int kt = 0; kt < 8; ++kt){
              bf16x8 a = *(const bf16x8*)(xb + ((size_t)(b0+m16)*T_ + t)*IN_ + kt*32 + q*8);
              #pragma unroll
              for (int G = 0; G < 4; ++G)
                acc[G] = __builtin_amdgcn_mfma_f32_16x16x32_bf16(
                    a, *(const bf16x8*)&P.wpool[(G*16+m16)*264 + kt*32 + q*8], acc[G], 0, 0, 0);
            }
            #pragma unroll 4
            for (int kt = 0; kt < 16; ++kt){
              bf16x8 a = *(const bf16x8*)(hin + (b0+m16)*512 + kt*32 + q*8);
              #pragma unroll
              for (int G = 0; G < 4; ++G)
                acc[G] = __builtin_amdgcn_mfma_f32_16x16x32_bf16(
                    a, *(const bf16x8*)&P.wpool[16896 + (G*16+m16)*520 + kt*32 + q*8], acc[G], 0, 0, 0);
            }
          } else {
            #pragma unroll 4
            for (int kt = 0; kt < 16; ++kt){
              bf16x8 a = *(const bf16x8*)(h0seq + ((size_t)t*64 + b0+m16)*512 + kt*32 + q*8);
              #pragma unroll
              for (int G = 0; G < 4; ++G)
                acc[G] = __builtin_amdgcn_mfma_f32_16x16x32_bf16(
                    a, *(const bf16x8*)&P.wpool[(G*16+m16)*520 + kt*32 + q*8], acc[G], 0, 0, 0);
            }
            #pragma unroll 4
            for (int kt = 0; kt < 16; ++kt){
              bf16x8 a = *(const bf16x8*)(hin + (b0+m16)*512 + kt*32 + q*8);
              #pragma unroll
              for (int G = 0; G < 4; ++G)
                acc[G] = __builtin_amdgcn_mfma_f32_16x16x32_bf16(
                    a, *(const bf16x8*)&P.wpool[33280 + (G*16+m16)*520 + kt*32 + q*8], acc[G], 0, 0, 0);
            }
          }
          #pragma unroll
          for (int v = 0; v < 4; ++v){
            int b = b0 + q*4 + v;
            float gi = acc[0][v], gf = acc[1][v], gg = acc[2][v], go = acc[3][v];
            float c_ = sigf(gf)*P.cst[b][m16] + sigf(gi)*tanhf(gg);
            P.cst[b][m16] = c_;
            float h = sigf(go)*tanhf(c_);
            bf16_t hb = (bf16_t)h;
            hout[b*512 + u0 + m16] = hb;
            if (!layer) h0seq[((size_t)t*64 + b)*512 + u0 + m16] = hb;
            else        outseq[((size_t)t*64 + b)*512 + u0 + m16] = hb;
          }
        }
      } else if (ps >= 2 && bid < 30){
        // xi tile for t2 = ps-2: rows bid*16..+16, batch-tile per wave
        const int t2 = ps - 2;
        const int b0 = (wv - 4) * 16;
        const int r = bid*16 + m16;          // < 480 (rows 471..479 zero-padded)
        float bv = bifp[r];
        f32x4 acc = {bv,bv,bv,bv};
        const bf16_t* arow = outseq + ((size_t)t2*64 + b0 + m16)*512 + q*8;
        const bf16_t* brow = Wifp + (size_t)r*512 + q*8;
        #pragma unroll 4
        for (int kt = 0; kt < 16; ++kt){
          acc = __builtin_amdgcn_mfma_f32_16x16x32_bf16(
              *(const bf16x8*)(arow + kt*32), *(const bf16x8*)(brow + kt*32), acc, 0, 0, 0);
        }
        #pragma unroll
        for (int v = 0; v < 4; ++v)
          XI[((size_t)t2*64 + b0 + q*4 + v)*480 + r] = acc[v];
      }
      treebar64(bar, (unsigned)ps, bid);
    }
  } else {
    // ===================== CONSUMER: memory recurrence ====================
    ConsShm& S = sh.c;
    const int b = bid - 64;
    const int quad = lane >> 4, li = lane & 15;
    unsigned prog = 0;   // tid0's cached view of the progress counter

    bf16x8 rowL[2][8], colL[2][8];
    #pragma unroll
    for (int g = 0; g < 2; ++g)
      #pragma unroll
      for (int ch = 0; ch < 8; ++ch)
        #pragma unroll
        for (int z = 0; z < 8; ++z){ rowL[g][ch][z] = (bf16_t)0.0f; colL[g][ch][z] = (bf16_t)0.0f; }

    if (tid < 256){
      S.ww_[tid] = DELTA_; S.usage[tid] = 0.0f; S.prec_[tid] = 0.0f;
      S.invn[tid] = 1.0f/(sqrtf(64.0f*DELTA_*DELTA_) + DELTA_);
      S.wwb[tid] = (bf16_t)DELTA_; S.precb[tid] = (bf16_t)0.0f;
      #pragma unroll
      for (int r = 0; r < 4; ++r) S.rw_[r][tid] = DELTA_;
    }
    for (int i = tid; i < 4*264; i += 512) ((bf16_t*)S.rwb)[i] = (bf16_t)DELTA_;
    for (int i = tid; i < 256*65; i += 512) ((float*)S.smem)[i] = DELTA_;
    __syncthreads();

    const int mH = tid >> 1, q2 = tid & 1;

    for (int t = 0; t < 32; ++t){
      // ---- R1: wait for XI[t] (prog >= t+3), then load ----
      if (tid == 0 && prog < (unsigned)(t + 3)){
        for (;;){
          prog = __hip_atomic_load(bar + 320, __ATOMIC_ACQUIRE, __HIP_MEMORY_SCOPE_AGENT);
          if (prog >= (unsigned)(t + 3)) break;
          __builtin_amdgcn_s_sleep(2);
        }
      }
      __syncthreads();
      if (tid < IFACE_) S.xib[tid] = XI[((size_t)t*64 + b)*480 + tid];
      __syncthreads();

      // ---- R2: parse interface vector ----
      if (wv < 4){
        float v = tanhf(S.xib[wv*64 + lane]);
        float s = wred(v*v);
        float vn = v/(sqrtf(s) + DELTA_);
        S.rkn4r[0][lane][wv] = vn; S.rkn4r[1][lane][wv] = vn;
      } else if (wv == 4){
        float v = tanhf(S.xib[260 + lane]);
        float s = wred(v*v);
        S.wkn[lane] = v/(sqrtf(s) + DELTA_);
      } else if (wv == 5){ S.ev_[lane] = sigf(S.xib[325 + lane]);
      } else if (wv == 6){ S.wvv[lane] = tanhf(S.xib[389 + lane]);
      } else {
        if (lane < 4)        S.rs_[lane] = softplusf(S.xib[256 + lane]);
        else if (lane == 4)  S.wsS = softplusf(S.xib[324]);
        else if (lane < 9)   S.fg_[lane-5] = sigf(S.xib[453 + (lane-5)]);
        else if (lane == 9)  S.agS = sigf(S.xib[457]);
        else if (lane == 10) S.wgS = sigf(S.xib[458]);
        else if (lane >= 16 && lane < 20){
          int r = lane - 16;
          float a0 = S.xib[459+r*3], a1 = S.xib[459+r*3+1], a2 = S.xib[459+r*3+2];
          float mx = fmaxf(a0, fmaxf(a1, a2));
          float e0 = expf(a0-mx), e1 = expf(a1-mx), e2 = expf(a2-mx);
          float s = e0+e1+e2;
          S.rm_[r][0]=e0/s; S.rm_[r][1]=e1/s; S.rm_[r][2]=e2/s;
        }
      }
      __syncthreads();

      // ---- R3: usage update (tid<256) + write-content partials (all) ----
      if (tid < 256){
        int m = tid;
        float us = S.usage[m] + (1.0f - S.usage[m])*S.ww_[m];
        float psi = (1.0f - S.fg_[0]*S.rw_[0][m]) * (1.0f - S.fg_[1]*S.rw_[1][m])
                  * (1.0f - S.fg_[2]*S.rw_[2][m]) * (1.0f - S.fg_[3]*S.rw_[3][m]);
        us *= psi;
        S.usage[m] = us;
        S.uu[m] = DELTA_ + (1.0f - DELTA_)*us;
      }
      { float acc = 0.0f;
        #pragma unroll
        for (int it = 0; it < 32; ++it){
          int w = q2*32 + it;
          acc += S.smem[mH][w] * S.wkn[w];
        }
        S.p2cT[q2][mH] = acc; }
      __syncthreads();

      // ---- R4: wave0: wcw combine + softmax ; waves 4-7: rank-sort ----
      if (wv == 0){
        #pragma unroll
        for (int z = 0; z < 4; ++z){
          int m = z*64 + lane;
          S.wcw[m] = S.wsS * (S.p2cT[0][m] + S.p2cT[1][m]) * S.invn[m];
        }
        softmax256_wave(S.wcw, lane);
      } else if (tid >= 256){
        const int i = tid - 256;
        const float ui = S.uu[i];
        int cnt = 0;
        #pragma unroll 8
        for (int k = 0; k < 64; ++k){
          f32x4 u4 = *(const f32x4*)&S.uu[k*4];
          #pragma unroll
          for (int z = 0; z < 4; ++z){
            int j = k*4 + z; float uj = u4[z];
            cnt += (uj < ui || (uj == ui && j < i)) ? 1 : 0;
          }
        }
        S.rank_[i] = cnt;
        S.su[cnt] = ui;
      }
      __syncthreads();

      // ---- R5: exclusive product scan of su -> scanA (wave 0) ----
      if (wv == 0){
        int base = lane*4;
        float v0 = S.su[base], v1 = S.su[base+1], v2 = S.su[base+2];
        float p1 = v0*v1, p2 = p1*v2, p3 = p2*S.su[base+3];
        float sc = p3;
        #pragma unroll
        for (int off = 1; off < 64; off <<= 1){
          float n = __shfl_up(sc, off, 64);
          if (lane >= off) sc *= n;
        }
        float exch = __shfl_up(sc, 1, 64);
        if (lane == 0) exch = 1.0f;
        S.scanA[base] = exch; S.scanA[base+1] = exch*v0;
        S.scanA[base+2] = exch*p1; S.scanA[base+3] = exch*p2;
      }
      __syncthreads();

      // ---- R7: ww (redundant per half) + mem erase/write + partials ----
      { const int m = mH;
        float al = (1.0f - S.uu[m]) * S.scanA[S.rank_[m]];
        float wm = S.wgS*(S.agS*al + (1.0f - S.agS)*S.wcw[m]);
        if (q2 == 0){ S.ww_[m] = wm; S.wwb[m] = (bf16_t)wm; }
        float s2 = 0.0f, sr0 = 0.0f, sr1 = 0.0f, sr2 = 0.0f, sr3 = 0.0f;
        #pragma unroll
        for (int it = 0; it < 32; ++it){
          int w = q2*32 + it;
          float mn = S.smem[m][w]*(1.0f - wm*S.ev_[w]) + wm*S.wvv[w];
          S.smem[m][w] = mn;
          s2 += mn*mn;
          f32x4 rk = *(const f32x4*)&S.rkn4r[q2][w][0];
          sr0 += mn*rk[0]; sr1 += mn*rk[1]; sr2 += mn*rk[2]; sr3 += mn*rk[3];
        }
        S.p5cT[0][q2][m] = s2;
        S.p5cT[1][q2][m] = sr0; S.p5cT[2][q2][m] = sr1;
        S.p5cT[3][q2][m] = sr2; S.p5cT[4][q2][m] = sr3; }
      __syncthreads();

      // ---- R8: norm + read-content pre-softmax (tid<256); wave4: wwsum ----
      if (tid < 256){
        int m = tid;
        float s2 = S.p5cT[0][0][m] + S.p5cT[0][1][m];
        float inv = 1.0f/(sqrtf(s2) + DELTA_);
        S.invn[m] = inv;
        #pragma unroll
        for (int r = 0; r < 4; ++r){
          float sr = S.p5cT[r+1][0][m] + S.p5cT[r+1][1][m];
          S.rcw_[r][m] = S.rs_[r]*sr*inv;
        }
      } else if (wv == 4){
        float s = wred(S.ww_[lane] + S.ww_[64+lane] + S.ww_[128+lane] + S.ww_[192+lane]);
        if (lane == 0) S.wwsumS = s;
      }
      __syncthreads();

      // ---- R9: link update + fwd/bwd via MFMA ----
      { float wown[2], pown[2], alpha[2];
        #pragma unroll
        for (int g = 0; g < 2; ++g){
          int o = wv*32 + g*16 + li;
          wown[g] = (float)S.wwb[o]; pown[g] = (float)S.precb[o];
          alpha[g] = 1.0f - wown[g];
        }
        f32x4 facc[2] = {{0,0,0,0},{0,0,0,0}}, bacc[2] = {{0,0,0,0},{0,0,0,0}};
        #pragma unroll
        for (int ch = 0; ch < 8; ++ch){
          const int cbase = ch*32 + quad*8;
          bf16x8 rwf = *(const bf16x8*)&S.rwb[li & 3][cbase];
          bf16x8 wwv = *(const bf16x8*)&S.wwb[cbase];
          bf16x8 pcv = *(const bf16x8*)&S.precb[cbase];
          float wcf[8], pcf[8];
          #pragma unroll
          for (int jj = 0; jj < 8; ++jj){ wcf[jj] = (float)wwv[jj]; pcf[jj] = (float)pcv[jj]; }
          #pragma unroll
          for (int g = 0; g < 2; ++g){
            const int o = wv*32 + g*16 + li;
            bf16x8 rl = rowL[g][ch];
            bf16x8 cl = colL[g][ch];
            #pragma unroll
            for (int jj = 0; jj < 8; ++jj){
              const int c = cbase + jj;
              float s = alpha[g] - wcf[jj];
              float vr = s*(float)rl[jj] + wown[g]*pcf[jj];
              float vc = s*(float)cl[jj] + wcf[jj]*pown[g];
              if (c == o){ vr = 0.0f; vc = 0.0f; }
              rl[jj] = (bf16_t)vr;
              cl[jj] = (bf16_t)vc;
            }
            rowL[g][ch] = rl; colL[g][ch] = cl;
            facc[g] = __builtin_amdgcn_mfma_f32_16x16x32_bf16(rl, rwf, facc[g], 0, 0, 0);
            bacc[g] = __builtin_amdgcn_mfma_f32_16x16x32_bf16(rwf, cl, bacc[g], 0, 0, 0);
          }
        }
        #pragma unroll
        for (int g = 0; g < 2; ++g){
          if (li < 4){
            #pragma unroll
            for (int z = 0; z < 4; ++z) S.fwd_[li][wv*32 + g*16 + quad*4 + z] = facc[g][z];
          }
          if (quad == 0){
            #pragma unroll
            for (int z = 0; z < 4; ++z) S.bwd_[z][wv*32 + g*16 + li] = bacc[g][z];
          }
        }
      }
      __syncthreads();

      // ---- R10: waves0-3: rcw softmax ; waves4-7: precedence ----
      if (wv < 4) softmax256_wave(S.rcw_[wv], lane);
      else {
        int m = tid - 256;
        float p = (1.0f - S.wwsumS)*S.prec_[m] + S.ww_[m];
        S.prec_[m] = p;
        S.precb[m] = (bf16_t)p;
      }
      __syncthreads();

      // ---- R11: new read weights ----
      { int r = tid >> 7, m0 = (tid & 127)*2;
        #pragma unroll
        for (int z = 0; z < 2; ++z){
          int m = m0 + z;
          float v = S.rm_[r][0]*S.bwd_[r][m] + S.rm_[r][1]*S.fwd_[r][m] + S.rm_[r][2]*S.rcw_[r][m];
          S.rw_[r][m] = v;
          S.rw4[m][r] = v;
          S.rwb[r][m] = (bf16_t)v;
        } }
      __syncthreads();

      // ---- R12: read vectors: wave-per-32-rows ----
      { float r0 = 0, r1 = 0, r2 = 0, r3 = 0;
        #pragma unroll
        for (int k = 0; k < 32; ++k){
          int m = wv*32 + k;
          f32x4 r4 = *(const f32x4*)&S.rw4[m][0];
          float mv = S.smem[m][lane];
          r0 += r4[0]*mv; r1 += r4[1]*mv; r2 += r4[2]*mv; r3 += r4[3]*mv;
        }
        S.rvp[wv][0][lane] = r0; S.rvp[wv][1][lane] = r1;
        S.rvp[wv][2][lane] = r2; S.rvp[wv][3][lane] = r3; }
      __syncthreads();

      // ---- R13: combine + store ----
      if (tid < 256){
        const int w = tid & 63, r = tid >> 6;
        float v = 0.0f;
        #pragma unroll
        for (int c = 0; c < 8; ++c) v += S.rvp[c][r][w];
        RVEC[((size_t)t*64 + b)*256 + tid] = v;
      }
      __syncthreads();
    }
  }
}

// ---------------------------------------------------------------------------
__global__ void k_tanhy(const bf16_t* __restrict__ outseq, const float* __restrict__ RVEC,
                        bf16_t* __restrict__ Y){
  const int n = 2048*768;
  for (int i = blockIdx.x*blockDim.x + threadIdx.x; i < n; i += gridDim.x*blockDim.x){
    int row = i / 768, j = i - row*768;
    float v = (j < 512) ? (float)outseq[(size_t)row*512 + j] : RVEC[(size_t)row*256 + (j - 512)];
    Y[i] = (bf16_t)tanhf(v);
  }
}

__global__ __launch_bounds__(256,1) void k_out(
    const bf16_t* __restrict__ Y, const bf16_t* __restrict__ Woutb,
    const float* __restrict__ boutf, void* __restrict__ dout,
    const int* __restrict__ flag)
{
  const int mf = *flag;
  const int mt = blockIdx.x;          // 0..127
  const int tid = threadIdx.x, lane = tid & 63, wv = tid >> 6;
  const int nt = blockIdx.y*4 + wv;   // 0..15
  const int m16 = lane & 15, q = lane >> 4;
  const int o = nt*16 + m16;
  float bv = boutf[o];
  f32x4 acc = {bv,bv,bv,bv};
  const bf16_t* arow = Y + (size_t)(mt*16 + m16)*768 + q*8;
  const bf16_t* brow = Woutb + (size_t)o*768 + q*8;
  for (int kt = 0; kt < 24; ++kt){
    acc = __builtin_amdgcn_mfma_f32_16x16x32_bf16(
        *(const bf16x8*)(arow + kt*32), *(const bf16x8*)(brow + kt*32), acc, 0, 0, 0);
  }
  #pragma unroll
  for (int v = 0; v < 4; ++v){
    int row = mt*16 + q*4 + v;        // = t*64 + b
    int b = row & 63, t = row >> 6;
    size_t idx = ((size_t)b*T_ + t)*256 + o;
    if (mf) ((float*)dout)[idx] = acc[v];
    else    ((bf16_t*)dout)[idx] = (bf16_t)acc[v];
  }
}

// ---------------------------------------------------------------------------
extern "C" void kernel_launch(void* const* d_in, const int* in_sizes, int n_in,
                              void* d_out, int out_size, void* d_ws, size_t ws_size,
                              hipStream_t stream)
{
  char* ws = (char*)d_ws;
  bf16_t* H0SEQ  = (bf16_t*)(ws + OFF_H0SEQ);
  bf16_t* OUTSEQ = (bf16_t*)(ws + OFF_OUTSEQ);
  bf16_t* H0BUF  = (bf16_t*)(ws + OFF_H0BUF);
  bf16_t* H1BUF  = (bf16_t*)(ws + OFF_H1BUF);
  float*  XI     = (float*) (ws + OFF_XI);
  float*  RVEC   = (float*) (ws + OFF_RVEC);
  bf16_t* YBF    = (bf16_t*)(ws + OFF_YBF);
  unsigned* BAR  = (unsigned*)(ws + OFF_BAR);
  int*    FLAG   = (int*)   (ws + OFF_BAR + 1408);
  bf16_t* XB     = (bf16_t*)(ws + OFF_XB);
  bf16_t* H0B    = (bf16_t*)(ws + OFF_H0B);
  bf16_t* W0     = (bf16_t*)(ws + OFF_W0);
  bf16_t* W1     = (bf16_t*)(ws + OFF_W1);
  bf16_t* W2     = (bf16_t*)(ws + OFF_W2);
  bf16_t* W3     = (bf16_t*)(ws + OFF_W3);
  bf16_t* WIFP   = (bf16_t*)(ws + OFF_WIF);
  bf16_t* WOUTB  = (bf16_t*)(ws + OFF_WOUTB);
  float*  BS0    = (float*) (ws + OFF_BS0);
  float*  BS1    = (float*) (ws + OFF_BS1);
  float*  BIFP   = (float*) (ws + OFF_BIF);
  float*  BOUTF  = (float*) (ws + OFF_BOUTF);

  k_detect<<<1, 256, 0, stream>>>((const unsigned short*)d_in[0], FLAG, BAR);
  k_convert<<<dim3(256, 9), 256, 0, stream>>>(
      d_in[0], d_in[1], d_in[2], d_in[3], d_in[4], d_in[5], d_in[6],
      d_in[7], d_in[8], d_in[9], d_in[10], d_in[11], d_in[12], d_in[13],
      XB, H0B, H0BUF, H1BUF, W0, W1, W2, W3, WIFP, WOUTB,
      BS0, BS1, BIFP, BOUTF, FLAG);
  k_main<<<128, 512, 0, stream>>>(XB, H0B, W0, W1, W2, W3, BS0, BS1,
                                  WIFP, BIFP, H0BUF, H1BUF, H0SEQ, OUTSEQ,
                                  XI, RVEC, BAR);
  k_tanhy<<<512, 256, 0, stream>>>(OUTSEQ, RVEC, YBF);
  k_out<<<dim3(128, 4), 256, 0, stream>>>(YBF, WOUTB, BOUTF, d_out, FLAG);
}